// Round 1
// baseline (594.209 us; speedup 1.0000x reference)
//
#include <hip/hip_runtime.h>

// ---------------- types / helpers ----------------
typedef __bf16 bf16x8 __attribute__((ext_vector_type(8)));
typedef float f32x4 __attribute__((ext_vector_type(4)));
typedef unsigned short u16x8 __attribute__((ext_vector_type(8)));

__device__ __forceinline__ unsigned short f2bf(float f) {
  union { float f; unsigned int u; } v; v.f = f;
  unsigned int r = v.u + 0x7fffu + ((v.u >> 16) & 1u);  // RNE
  return (unsigned short)(r >> 16);
}

__device__ __forceinline__ void async16(const unsigned short* g, unsigned short* l) {
  __builtin_amdgcn_global_load_lds(
      (const __attribute__((address_space(1))) unsigned int*)g,
      (__attribute__((address_space(3))) unsigned int*)l, 16, 0, 0);
}

// ---------------- f32 -> bf16 convert ----------------
__global__ void cvt_bf16(const float* __restrict__ s, unsigned short* __restrict__ d, int n4) {
  int i = blockIdx.x * 256 + threadIdx.x;
  if (i >= n4) return;
  float4 v = ((const float4*)s)[i];
  ushort4 o;
  o.x = f2bf(v.x); o.y = f2bf(v.y); o.z = f2bf(v.z); o.w = f2bf(v.w);
  ((ushort4*)d)[i] = o;
}

// ---------------- LayerNorm (per 1024-row) -> bf16 ----------------
__global__ __launch_bounds__(256) void ln_bf16(
    const float* __restrict__ src, unsigned short* __restrict__ dst,
    const float* __restrict__ g, const float* __restrict__ be) {
  const int row = blockIdx.x, tid = threadIdx.x;
  const float4 v = ((const float4*)(src + (size_t)row * 1024))[tid];
  float s = v.x + v.y + v.z + v.w;
  float qq = v.x * v.x + v.y * v.y + v.z * v.z + v.w * v.w;
#pragma unroll
  for (int off = 32; off; off >>= 1) { s += __shfl_xor(s, off); qq += __shfl_xor(qq, off); }
  __shared__ float ps[4], pq[4];
  const int w = tid >> 6, lane = tid & 63;
  if (lane == 0) { ps[w] = s; pq[w] = qq; }
  __syncthreads();
  if (tid == 0) { ps[0] = ps[0] + ps[1] + ps[2] + ps[3]; pq[0] = pq[0] + pq[1] + pq[2] + pq[3]; }
  __syncthreads();
  const float mu = ps[0] * (1.f / 1024.f);
  const float var = pq[0] * (1.f / 1024.f) - mu * mu;
  const float rs = rsqrtf(var + 1e-5f);
  const float4 gv = ((const float4*)g)[tid];
  const float4 bv = ((const float4*)be)[tid];
  ushort4 o;
  o.x = f2bf((v.x - mu) * rs * gv.x + bv.x);
  o.y = f2bf((v.y - mu) * rs * gv.y + bv.y);
  o.z = f2bf((v.z - mu) * rs * gv.z + bv.z);
  o.w = f2bf((v.w - mu) * rs * gv.w + bv.w);
  ((ushort4*)(dst + (size_t)row * 1024))[tid] = o;
}

// ---------------- GEMM: C[M,N] = A[M,K] @ B[N,K]^T + bias, m97-style ----------------
// EPI: 0 = (acc+b)*scale -> bf16 ; 1 = acc+b -> bf16 ; 2 = acc+b+resid -> f32 ; 3 = relu(acc+b) -> bf16
template <int EPI>
__global__ __launch_bounds__(256) void gemm_bt(
    const unsigned short* __restrict__ A, const unsigned short* __restrict__ Bw,
    const float* __restrict__ bias, const float* __restrict__ resid,
    void* __restrict__ Cout, int M, int N, int K, float scale) {
  __shared__ __align__(16) unsigned short lA[128 * 32];
  __shared__ __align__(16) unsigned short lB[128 * 32];
  const int tid = threadIdx.x;
  const int w = tid >> 6, lane = tid & 63;
  const int lr = lane & 15, lq = lane >> 4;
  const int bm = blockIdx.y, bn = blockIdx.x;
  const unsigned short* Ab = A + (size_t)bm * 128 * K;
  const unsigned short* Bb = Bw + (size_t)bn * 128 * K;
  const int wm = (w & 1) << 6, wn = (w >> 1) << 6;
  f32x4 acc[4][4] = {};
  const int kiters = K >> 5;
  const int c0 = tid, c1 = 256 + tid;
  const int r0 = c0 >> 2, o0 = (c0 & 3) << 3;
  const int r1 = c1 >> 2, o1 = (c1 & 3) << 3;
  for (int kt = 0; kt < kiters; ++kt) {
    const int kb = kt << 5;
    __syncthreads();
    async16(Ab + (size_t)r0 * K + kb + o0, lA + c0 * 8);
    async16(Bb + (size_t)r0 * K + kb + o0, lB + c0 * 8);
    async16(Ab + (size_t)r1 * K + kb + o1, lA + c1 * 8);
    async16(Bb + (size_t)r1 * K + kb + o1, lB + c1 * 8);
    __syncthreads();
    bf16x8 af[4], bfr[4];
#pragma unroll
    for (int i = 0; i < 4; ++i) af[i] = *(const bf16x8*)(lA + (wm + i * 16 + lr) * 32 + lq * 8);
#pragma unroll
    for (int i = 0; i < 4; ++i) bfr[i] = *(const bf16x8*)(lB + (wn + i * 16 + lr) * 32 + lq * 8);
#pragma unroll
    for (int i = 0; i < 4; ++i)
#pragma unroll
      for (int j = 0; j < 4; ++j)
        acc[i][j] = __builtin_amdgcn_mfma_f32_16x16x32_bf16(af[i], bfr[j], acc[i][j], 0, 0, 0);
  }
#pragma unroll
  for (int i = 0; i < 4; ++i) {
#pragma unroll
    for (int j = 0; j < 4; ++j) {
      const int colg = bn * 128 + wn + j * 16 + lr;
      const float bi = bias[colg];
      const int rowg0 = bm * 128 + wm + i * 16 + lq * 4;
#pragma unroll
      for (int r = 0; r < 4; ++r) {
        const size_t idx = (size_t)(rowg0 + r) * N + colg;
        const float val = acc[i][j][r] + bi;
        if (EPI == 0) ((unsigned short*)Cout)[idx] = f2bf(val * scale);
        else if (EPI == 1) ((unsigned short*)Cout)[idx] = f2bf(val);
        else if (EPI == 2) ((float*)Cout)[idx] = val + resid[idx];
        else ((unsigned short*)Cout)[idx] = f2bf(fmaxf(val, 0.f));
      }
    }
  }
}

// ---------------- V transpose: vt[head][d][k] ----------------
__global__ __launch_bounds__(256) void vtrans(const unsigned short* __restrict__ v,
                                              unsigned short* __restrict__ vt) {
  __shared__ __align__(16) unsigned short ls[64][80];
  const int kc = blockIdx.x, n = blockIdx.y;
  const int b = n >> 4, h = n & 15;
  const int tid = threadIdx.x;
#pragma unroll
  for (int i = 0; i < 2; ++i) {
    const int c = i * 256 + tid;
    const int kk = c >> 3, dc = (c & 7) << 3;
    u16x8 val = *(const u16x8*)(v + ((size_t)((kc * 64 + kk) * 16 + b)) * 1024 + h * 64 + dc);
    *(u16x8*)&ls[kk][dc] = val;
  }
  __syncthreads();
#pragma unroll
  for (int i = 0; i < 2; ++i) {
    const int c = i * 256 + tid;
    const int d = c >> 3, kx = (c & 7) << 3;
    u16x8 o;
#pragma unroll
    for (int j = 0; j < 8; ++j) o[j] = ls[kx + j][d];
    *(u16x8*)(vt + ((size_t)n * 64 + d) * 448 + kc * 64 + kx) = o;
  }
}

// ---------------- fused attention: QK^T -> suppression -> softmax -> PV ----------------
// grid (12 qtiles of 32 rows, 256 heads), block 256
__global__ __launch_bounds__(256) void attn_kernel(
    const unsigned short* __restrict__ q, const unsigned short* __restrict__ k,
    const unsigned short* __restrict__ vt, unsigned short* __restrict__ attn) {
  __shared__ __align__(16) float S[32][452];  // 448 + 4 pad: breaks power-of-2 bank stride
  const int qt = blockIdx.x, n = blockIdx.y;
  const int b = n >> 4, h = n & 15;
  const int tid = threadIdx.x, w = tid >> 6, lane = tid & 63;
  const int lr = lane & 15, lq = lane >> 4;

  // Q fragments (held in regs across phase 1)
  bf16x8 af[2][2];
#pragma unroll
  for (int mf = 0; mf < 2; ++mf)
#pragma unroll
    for (int ks = 0; ks < 2; ++ks) {
      const int t = qt * 32 + mf * 16 + lr;
      af[mf][ks] = *(const bf16x8*)(q + ((size_t)t * 16 + b) * 1024 + h * 64 + ks * 32 + lq * 8);
    }

  // phase 1: scores. wave w owns k-cols [w*112, w*112+112)
  const int cw = w * 112;
  for (int nf = 0; nf < 7; ++nf) {
    const int n0 = cw + nf * 16;
    const unsigned short* kp = k + ((size_t)(n0 + lr) * 16 + b) * 1024 + h * 64 + lq * 8;
    bf16x8 b0 = *(const bf16x8*)(kp);
    bf16x8 b1 = *(const bf16x8*)(kp + 32);
#pragma unroll
    for (int mf = 0; mf < 2; ++mf) {
      f32x4 acc = {0.f, 0.f, 0.f, 0.f};
      acc = __builtin_amdgcn_mfma_f32_16x16x32_bf16(af[mf][0], b0, acc, 0, 0, 0);
      acc = __builtin_amdgcn_mfma_f32_16x16x32_bf16(af[mf][1], b1, acc, 0, 0, 0);
#pragma unroll
      for (int r = 0; r < 4; ++r) S[mf * 16 + lq * 4 + r][n0 + lr] = acc[r];
    }
  }
  __syncthreads();

  // phase 2: softmax + suppression + re-softmax, one wave-row at a time (8 rows/wave)
  for (int ri = 0; ri < 8; ++ri) {
    const int r = w * 8 + ri;
    float x[7], e[7], p[7];
    float m = -3.4e38f;
#pragma unroll
    for (int j = 0; j < 7; ++j) { x[j] = S[r][lane + 64 * j]; m = fmaxf(m, x[j]); }
#pragma unroll
    for (int off = 32; off; off >>= 1) m = fmaxf(m, __shfl_xor(m, off));
    float s = 0.f;
#pragma unroll
    for (int j = 0; j < 7; ++j) { e[j] = expf(x[j] - m); s += e[j]; }
#pragma unroll
    for (int off = 32; off; off >>= 1) s += __shfl_xor(s, off);
    const float inv = 1.f / s;
    float sp = 0.f, cnt = 0.f;
#pragma unroll
    for (int j = 0; j < 7; ++j) { p[j] = e[j] * inv; sp += p[j]; if (p[j] > 0.f) cnt += 1.f; }
#pragma unroll
    for (int off = 32; off; off >>= 1) { sp += __shfl_xor(sp, off); cnt += __shfl_xor(cnt, off); }
    const float mean = sp / cnt;
    float dv = 0.f;
#pragma unroll
    for (int j = 0; j < 7; ++j) { const float dd = p[j] - mean; if (p[j] > 0.f) dv += dd * dd; }
#pragma unroll
    for (int off = 32; off; off >>= 1) dv += __shfl_xor(dv, off);
    const float var = dv / (cnt - 1.f);
    const float thr = mean - 0.5f * sqrtf(var);
    // max element always survives (p_max >= mean >= thr) => same max, reuse e[]
    float s2 = 0.f;
#pragma unroll
    for (int j = 0; j < 7; ++j) if (!(p[j] < thr)) s2 += e[j];
#pragma unroll
    for (int off = 32; off; off >>= 1) s2 += __shfl_xor(s2, off);
    const float inv2 = 1.f / s2;
#pragma unroll
    for (int j = 0; j < 7; ++j) S[r][lane + 64 * j] = (p[j] < thr) ? 0.f : e[j] * inv2;
  }
  __syncthreads();

  // phase 3: PV. wave w: m-frag (w&1), d-half (w>>1)*32
  const int mf = w & 1, dh = (w >> 1) * 32;
  const int m0 = mf * 16;
  f32x4 acc0 = {0.f, 0.f, 0.f, 0.f}, acc1 = {0.f, 0.f, 0.f, 0.f};
  for (int kt = 0; kt < 14; ++kt) {
    const int k0 = kt * 32;
    const float* sp2 = &S[m0 + lr][k0 + lq * 8];
    f32x4 lo = *(const f32x4*)sp2;
    f32x4 hi = *(const f32x4*)(sp2 + 4);
    union { u16x8 u; bf16x8 bv; } cv;
#pragma unroll
    for (int j = 0; j < 4; ++j) { cv.u[j] = f2bf(lo[j]); cv.u[4 + j] = f2bf(hi[j]); }
    const unsigned short* vp = vt + ((size_t)n * 64 + dh + lr) * 448 + k0 + lq * 8;
    bf16x8 bb0 = *(const bf16x8*)(vp);
    bf16x8 bb1 = *(const bf16x8*)(vp + (size_t)16 * 448);
    acc0 = __builtin_amdgcn_mfma_f32_16x16x32_bf16(cv.bv, bb0, acc0, 0, 0, 0);
    acc1 = __builtin_amdgcn_mfma_f32_16x16x32_bf16(cv.bv, bb1, acc1, 0, 0, 0);
  }
#pragma unroll
  for (int r = 0; r < 4; ++r) {
    const int t = qt * 32 + m0 + lq * 4 + r;
    unsigned short* op = attn + ((size_t)t * 16 + b) * 1024 + h * 64 + dh + lr;
    op[0] = f2bf(acc0[r]);
    op[16] = f2bf(acc1[r]);
  }
}

// ---------------- launch ----------------
extern "C" void kernel_launch(void* const* d_in, const int* in_sizes, int n_in,
                              void* d_out, int out_size, void* d_ws, size_t ws_size,
                              hipStream_t stream) {
  (void)in_sizes; (void)n_in; (void)out_size; (void)ws_size;
  const float* x    = (const float*)d_in[0];
  const float* mem  = (const float*)d_in[1];
  const float* q_w  = (const float*)d_in[2];
  const float* q_b  = (const float*)d_in[3];
  const float* k_w  = (const float*)d_in[4];
  const float* k_b  = (const float*)d_in[5];
  const float* v_w  = (const float*)d_in[6];
  const float* v_b  = (const float*)d_in[7];
  const float* o_w  = (const float*)d_in[8];
  const float* o_b  = (const float*)d_in[9];
  const float* ln1w = (const float*)d_in[10];
  const float* ln1b = (const float*)d_in[11];
  const float* f1w  = (const float*)d_in[12];
  const float* f1b  = (const float*)d_in[13];
  const float* f2w  = (const float*)d_in[14];
  const float* f2b  = (const float*)d_in[15];
  const float* ln2w = (const float*)d_in[16];
  const float* ln2b = (const float*)d_in[17];

  unsigned short* WQ   = (unsigned short*)d_ws;        // 1048576
  unsigned short* WK   = WQ + 1048576;
  unsigned short* WV   = WK + 1048576;
  unsigned short* WO   = WV + 1048576;
  unsigned short* WF1  = WO + 1048576;                 // 4194304
  unsigned short* WF2  = WF1 + 4194304;                // 4194304
  unsigned short* ABUF = WF2 + 4194304;                // 7340032 (memory rows 0..1023, xn rows 1024..7167)
  unsigned short* QB   = ABUF + 7340032;               // 6291456
  unsigned short* KB   = QB + 6291456;                 // 7340032
  unsigned short* VB   = KB + 7340032;                 // 7340032
  unsigned short* VT   = VB + 7340032;                 // 7340032
  unsigned short* ATTN = VT + 7340032;                 // 6291456
  float*          X2   = (float*)(ATTN + 6291456);     // 6291456 f32  -> total 128 MiB
  unsigned short* XN2  = ATTN;                         // alias (attn dead after out-proj)
  unsigned short* HB   = ABUF;                         // alias (A/q/k dead after attention), 25165824 elems

  // weight + memory converts
  cvt_bf16<<<1024, 256, 0, stream>>>(q_w, WQ, 262144);
  cvt_bf16<<<1024, 256, 0, stream>>>(k_w, WK, 262144);
  cvt_bf16<<<1024, 256, 0, stream>>>(v_w, WV, 262144);
  cvt_bf16<<<1024, 256, 0, stream>>>(o_w, WO, 262144);
  cvt_bf16<<<4096, 256, 0, stream>>>(f1w, WF1, 1048576);
  cvt_bf16<<<4096, 256, 0, stream>>>(f2w, WF2, 1048576);
  cvt_bf16<<<1024, 256, 0, stream>>>(mem, ABUF, 262144);

  // LN1 -> xn (rows 1024.. of ABUF)
  ln_bf16<<<6144, 256, 0, stream>>>(x, ABUF + 1048576, ln1w, ln1b);

  // QKV projections (summary row is dead code: out_and_mem[:-1] drops it)
  gemm_bt<0><<<dim3(8, 48), 256, 0, stream>>>(ABUF + 1048576, WQ, q_b, nullptr, QB, 6144, 1024, 1024, 0.125f);
  gemm_bt<1><<<dim3(8, 56), 256, 0, stream>>>(ABUF, WK, k_b, nullptr, KB, 7168, 1024, 1024, 1.f);
  gemm_bt<1><<<dim3(8, 56), 256, 0, stream>>>(ABUF, WV, v_b, nullptr, VB, 7168, 1024, 1024, 1.f);

  vtrans<<<dim3(7, 256), 256, 0, stream>>>(VB, VT);
  attn_kernel<<<dim3(12, 256), 256, 0, stream>>>(QB, KB, VT, ATTN);

  // out-proj + residual -> X2 (f32)
  gemm_bt<2><<<dim3(8, 48), 256, 0, stream>>>(ATTN, WO, o_b, x, X2, 6144, 1024, 1024, 1.f);

  // LN2 -> xn2
  ln_bf16<<<6144, 256, 0, stream>>>(X2, XN2, ln2w, ln2b);

  // FFN
  gemm_bt<3><<<dim3(32, 48), 256, 0, stream>>>(XN2, WF1, f1b, nullptr, HB, 6144, 4096, 1024, 1.f);
  gemm_bt<2><<<dim3(8, 48), 256, 0, stream>>>(HB, WF2, f2b, X2, d_out, 6144, 1024, 4096, 1.f);
}

// Round 2
// 583.190 us; speedup vs baseline: 1.0189x; 1.0189x over previous
//
#include <hip/hip_runtime.h>

// ---------------- types / helpers ----------------
typedef __bf16 bf16x8 __attribute__((ext_vector_type(8)));
typedef float f32x4 __attribute__((ext_vector_type(4)));
typedef unsigned short u16x8 __attribute__((ext_vector_type(8)));

__device__ __forceinline__ unsigned short f2bf(float f) {
  union { float f; unsigned int u; } v; v.f = f;
  unsigned int r = v.u + 0x7fffu + ((v.u >> 16) & 1u);  // RNE
  return (unsigned short)(r >> 16);
}

__device__ __forceinline__ void async16(const unsigned short* g, unsigned short* l) {
  __builtin_amdgcn_global_load_lds(
      (const __attribute__((address_space(1))) unsigned int*)g,
      (__attribute__((address_space(3))) unsigned int*)l, 16, 0, 0);
}

// ---------------- f32 -> bf16 convert ----------------
__global__ void cvt_bf16(const float* __restrict__ s, unsigned short* __restrict__ d, int n4) {
  int i = blockIdx.x * 256 + threadIdx.x;
  if (i >= n4) return;
  float4 v = ((const float4*)s)[i];
  ushort4 o;
  o.x = f2bf(v.x); o.y = f2bf(v.y); o.z = f2bf(v.z); o.w = f2bf(v.w);
  ((ushort4*)d)[i] = o;
}

// ---------------- LayerNorm (per 1024-row) -> bf16 ----------------
__global__ __launch_bounds__(256) void ln_bf16(
    const float* __restrict__ src, unsigned short* __restrict__ dst,
    const float* __restrict__ g, const float* __restrict__ be) {
  const int row = blockIdx.x, tid = threadIdx.x;
  const float4 v = ((const float4*)(src + (size_t)row * 1024))[tid];
  float s = v.x + v.y + v.z + v.w;
  float qq = v.x * v.x + v.y * v.y + v.z * v.z + v.w * v.w;
#pragma unroll
  for (int off = 32; off; off >>= 1) { s += __shfl_xor(s, off); qq += __shfl_xor(qq, off); }
  __shared__ float ps[4], pq[4];
  const int w = tid >> 6, lane = tid & 63;
  if (lane == 0) { ps[w] = s; pq[w] = qq; }
  __syncthreads();
  if (tid == 0) { ps[0] = ps[0] + ps[1] + ps[2] + ps[3]; pq[0] = pq[0] + pq[1] + pq[2] + pq[3]; }
  __syncthreads();
  const float mu = ps[0] * (1.f / 1024.f);
  const float var = pq[0] * (1.f / 1024.f) - mu * mu;
  const float rs = rsqrtf(var + 1e-5f);
  const float4 gv = ((const float4*)g)[tid];
  const float4 bv = ((const float4*)be)[tid];
  ushort4 o;
  o.x = f2bf((v.x - mu) * rs * gv.x + bv.x);
  o.y = f2bf((v.y - mu) * rs * gv.y + bv.y);
  o.z = f2bf((v.z - mu) * rs * gv.z + bv.z);
  o.w = f2bf((v.w - mu) * rs * gv.w + bv.w);
  ((ushort4*)(dst + (size_t)row * 1024))[tid] = o;
}

// ---------------- GEMM: C[M,N] = A[M,K] @ B[N,K]^T + bias, m97-style ----------------
// EPI: 0 = (acc+b)*scale -> bf16 ; 1 = acc+b -> bf16 ; 2 = acc+b+resid -> f32 ;
//      3 = relu(acc+b) -> bf16 ; 4 = (acc+b)*scale -> bf16 head-major [b*16+h][t][d] (T = M/16)
template <int EPI>
__global__ __launch_bounds__(256) void gemm_bt(
    const unsigned short* __restrict__ A, const unsigned short* __restrict__ Bw,
    const float* __restrict__ bias, const float* __restrict__ resid,
    void* __restrict__ Cout, int M, int N, int K, float scale) {
  __shared__ __align__(16) unsigned short lA[128 * 32];
  __shared__ __align__(16) unsigned short lB[128 * 32];
  const int tid = threadIdx.x;
  const int w = tid >> 6, lane = tid & 63;
  const int lr = lane & 15, lq = lane >> 4;
  const int bm = blockIdx.y, bn = blockIdx.x;
  const unsigned short* Ab = A + (size_t)bm * 128 * K;
  const unsigned short* Bb = Bw + (size_t)bn * 128 * K;
  const int wm = (w & 1) << 6, wn = (w >> 1) << 6;
  f32x4 acc[4][4] = {};
  const int kiters = K >> 5;
  const int c0 = tid, c1 = 256 + tid;
  const int r0 = c0 >> 2, o0 = (c0 & 3) << 3;
  const int r1 = c1 >> 2, o1 = (c1 & 3) << 3;
  for (int kt = 0; kt < kiters; ++kt) {
    const int kb = kt << 5;
    __syncthreads();
    async16(Ab + (size_t)r0 * K + kb + o0, lA + c0 * 8);
    async16(Bb + (size_t)r0 * K + kb + o0, lB + c0 * 8);
    async16(Ab + (size_t)r1 * K + kb + o1, lA + c1 * 8);
    async16(Bb + (size_t)r1 * K + kb + o1, lB + c1 * 8);
    __syncthreads();
    bf16x8 af[4], bfr[4];
#pragma unroll
    for (int i = 0; i < 4; ++i) af[i] = *(const bf16x8*)(lA + (wm + i * 16 + lr) * 32 + lq * 8);
#pragma unroll
    for (int i = 0; i < 4; ++i) bfr[i] = *(const bf16x8*)(lB + (wn + i * 16 + lr) * 32 + lq * 8);
#pragma unroll
    for (int i = 0; i < 4; ++i)
#pragma unroll
      for (int j = 0; j < 4; ++j)
        acc[i][j] = __builtin_amdgcn_mfma_f32_16x16x32_bf16(af[i], bfr[j], acc[i][j], 0, 0, 0);
  }
#pragma unroll
  for (int i = 0; i < 4; ++i) {
#pragma unroll
    for (int j = 0; j < 4; ++j) {
      const int colg = bn * 128 + wn + j * 16 + lr;
      const float bi = bias[colg];
      const int rowg0 = bm * 128 + wm + i * 16 + lq * 4;
#pragma unroll
      for (int r = 0; r < 4; ++r) {
        const int rowg = rowg0 + r;
        const float val = acc[i][j][r] + bi;
        if (EPI == 4) {
          const int T = M >> 4;
          const int t = rowg >> 4, bb = rowg & 15, hh = colg >> 6, dd = colg & 63;
          ((unsigned short*)Cout)[(((size_t)(bb * 16 + hh) * T + t) * 64 + dd)] = f2bf(val * scale);
        } else {
          const size_t idx = (size_t)rowg * N + colg;
          if (EPI == 0) ((unsigned short*)Cout)[idx] = f2bf(val * scale);
          else if (EPI == 1) ((unsigned short*)Cout)[idx] = f2bf(val);
          else if (EPI == 2) ((float*)Cout)[idx] = val + resid[idx];
          else ((unsigned short*)Cout)[idx] = f2bf(fmaxf(val, 0.f));
        }
      }
    }
  }
}

// ---------------- V transpose: vb[n][t][d] -> vt[n][d][t] ----------------
__global__ __launch_bounds__(256) void vtrans(const unsigned short* __restrict__ vb,
                                              unsigned short* __restrict__ vt) {
  __shared__ __align__(16) unsigned short ls[64][80];
  const int kc = blockIdx.x, n = blockIdx.y;
  const int tid = threadIdx.x;
#pragma unroll
  for (int i = 0; i < 2; ++i) {
    const int c = i * 256 + tid;
    const int kk = c >> 3, dc = (c & 7) << 3;
    u16x8 val = *(const u16x8*)(vb + ((size_t)n * 448 + kc * 64 + kk) * 64 + dc);
    *(u16x8*)&ls[kk][dc] = val;
  }
  __syncthreads();
#pragma unroll
  for (int i = 0; i < 2; ++i) {
    const int c = i * 256 + tid;
    const int d = c >> 3, kx = (c & 7) << 3;
    u16x8 o;
#pragma unroll
    for (int j = 0; j < 8; ++j) o[j] = ls[kx + j][d];
    *(u16x8*)(vt + ((size_t)n * 64 + d) * 448 + kc * 64 + kx) = o;
  }
}

// ---------------- fused attention: QK^T -> suppression -> softmax -> PV ----------------
// 1D grid 6144 = 8 XCD x 32 heads x 24 qtiles(16 rows). All loads head-major coalesced.
__global__ __launch_bounds__(256) void attn_kernel(
    const unsigned short* __restrict__ qt_, const unsigned short* __restrict__ kt_,
    const unsigned short* __restrict__ vt_, unsigned short* __restrict__ attn) {
  __shared__ __align__(16) float S[16][452];  // 28.9 KB -> 4-5 blocks/CU
  const int id = blockIdx.x;
  const int xcd = id & 7, j0 = id >> 3;
  const int n = xcd * 32 + (j0 & 31), qt = j0 >> 5;
  const int b = n >> 4, h = n & 15;
  const int tid = threadIdx.x, w = tid >> 6, lane = tid & 63;
  const int lr = lane & 15, lq = lane >> 4;

  // Q fragments: rows qt*16+lr, contiguous per head
  const unsigned short* qp = qt_ + ((size_t)n * 384 + qt * 16 + lr) * 64 + lq * 8;
  const bf16x8 a0 = *(const bf16x8*)qp;
  const bf16x8 a1 = *(const bf16x8*)(qp + 32);

  // phase 1: wave w owns score cols [w*112, w*112+112). Pipeline all K loads first.
  const int cw = w * 112;
  bf16x8 kb0[7], kb1[7];
#pragma unroll
  for (int nf = 0; nf < 7; ++nf) {
    const unsigned short* kp = kt_ + ((size_t)n * 448 + cw + nf * 16 + lr) * 64 + lq * 8;
    kb0[nf] = *(const bf16x8*)kp;
    kb1[nf] = *(const bf16x8*)(kp + 32);
  }
#pragma unroll
  for (int nf = 0; nf < 7; ++nf) {
    f32x4 acc = {0.f, 0.f, 0.f, 0.f};
    acc = __builtin_amdgcn_mfma_f32_16x16x32_bf16(a0, kb0[nf], acc, 0, 0, 0);
    acc = __builtin_amdgcn_mfma_f32_16x16x32_bf16(a1, kb1[nf], acc, 0, 0, 0);
#pragma unroll
    for (int r = 0; r < 4; ++r) S[lq * 4 + r][cw + nf * 16 + lr] = acc[r];
  }
  __syncthreads();

  // phase 2: softmax + suppression + re-softmax; wave w rows [w*4, w*4+4)
  for (int ri = 0; ri < 4; ++ri) {
    const int r = w * 4 + ri;
    float x[7], e[7], p[7];
    float m = -3.4e38f;
#pragma unroll
    for (int j = 0; j < 7; ++j) { x[j] = S[r][lane + 64 * j]; m = fmaxf(m, x[j]); }
#pragma unroll
    for (int off = 32; off; off >>= 1) m = fmaxf(m, __shfl_xor(m, off));
    float s = 0.f;
#pragma unroll
    for (int j = 0; j < 7; ++j) { e[j] = __expf(x[j] - m); s += e[j]; }
#pragma unroll
    for (int off = 32; off; off >>= 1) s += __shfl_xor(s, off);
    const float inv = 1.f / s;
    float sp = 0.f, cnt = 0.f;
#pragma unroll
    for (int j = 0; j < 7; ++j) { p[j] = e[j] * inv; sp += p[j]; if (p[j] > 0.f) cnt += 1.f; }
#pragma unroll
    for (int off = 32; off; off >>= 1) { sp += __shfl_xor(sp, off); cnt += __shfl_xor(cnt, off); }
    const float mean = sp / cnt;
    float dv = 0.f;
#pragma unroll
    for (int j = 0; j < 7; ++j) { const float dd = p[j] - mean; if (p[j] > 0.f) dv += dd * dd; }
#pragma unroll
    for (int off = 32; off; off >>= 1) dv += __shfl_xor(dv, off);
    const float var = dv / (cnt - 1.f);
    const float thr = mean - 0.5f * sqrtf(var);
    // max element always survives (p_max >= mean >= thr) => row max unchanged, reuse e[]
    float s2 = 0.f;
#pragma unroll
    for (int j = 0; j < 7; ++j) if (!(p[j] < thr)) s2 += e[j];
#pragma unroll
    for (int off = 32; off; off >>= 1) s2 += __shfl_xor(s2, off);
    const float inv2 = 1.f / s2;
    // write P back IN PLACE as bf16 (row r f32 data is fully in regs by now)
    unsigned short* prow = (unsigned short*)&S[r][0];
#pragma unroll
    for (int j = 0; j < 7; ++j)
      prow[lane + 64 * j] = (p[j] < thr) ? (unsigned short)0 : f2bf(e[j] * inv2);
  }
  __syncthreads();

  // phase 3: PV. wave w owns d-slice [w*16, w*16+16). P is bf16 rows of S.
  const unsigned short* Pb = (const unsigned short*)&S[0][0];
  bf16x8 vb0[7], vb1[7];
#pragma unroll
  for (int kt2 = 0; kt2 < 7; ++kt2) {
    const unsigned short* vp = vt_ + ((size_t)n * 64 + w * 16 + lr) * 448 + kt2 * 64 + lq * 8;
    vb0[kt2] = *(const bf16x8*)vp;
    vb1[kt2] = *(const bf16x8*)(vp + 32);
  }
  f32x4 acc3 = {0.f, 0.f, 0.f, 0.f};
#pragma unroll
  for (int kt2 = 0; kt2 < 7; ++kt2) {
    const bf16x8 af0 = *(const bf16x8*)(Pb + (size_t)lr * 904 + kt2 * 64 + lq * 8);
    const bf16x8 af1 = *(const bf16x8*)(Pb + (size_t)lr * 904 + kt2 * 64 + 32 + lq * 8);
    acc3 = __builtin_amdgcn_mfma_f32_16x16x32_bf16(af0, vb0[kt2], acc3, 0, 0, 0);
    acc3 = __builtin_amdgcn_mfma_f32_16x16x32_bf16(af1, vb1[kt2], acc3, 0, 0, 0);
  }
#pragma unroll
  for (int r = 0; r < 4; ++r) {
    const int l = qt * 16 + lq * 4 + r;
    attn[((size_t)l * 16 + b) * 1024 + h * 64 + w * 16 + lr] = f2bf(acc3[r]);
  }
}

// ---------------- launch ----------------
extern "C" void kernel_launch(void* const* d_in, const int* in_sizes, int n_in,
                              void* d_out, int out_size, void* d_ws, size_t ws_size,
                              hipStream_t stream) {
  (void)in_sizes; (void)n_in; (void)out_size; (void)ws_size;
  const float* x    = (const float*)d_in[0];
  const float* mem  = (const float*)d_in[1];
  const float* q_w  = (const float*)d_in[2];
  const float* q_b  = (const float*)d_in[3];
  const float* k_w  = (const float*)d_in[4];
  const float* k_b  = (const float*)d_in[5];
  const float* v_w  = (const float*)d_in[6];
  const float* v_b  = (const float*)d_in[7];
  const float* o_w  = (const float*)d_in[8];
  const float* o_b  = (const float*)d_in[9];
  const float* ln1w = (const float*)d_in[10];
  const float* ln1b = (const float*)d_in[11];
  const float* f1w  = (const float*)d_in[12];
  const float* f1b  = (const float*)d_in[13];
  const float* f2w  = (const float*)d_in[14];
  const float* f2b  = (const float*)d_in[15];
  const float* ln2w = (const float*)d_in[16];
  const float* ln2b = (const float*)d_in[17];

  unsigned short* WQ   = (unsigned short*)d_ws;        // 1048576
  unsigned short* WK   = WQ + 1048576;
  unsigned short* WV   = WK + 1048576;
  unsigned short* WO   = WV + 1048576;
  unsigned short* WF1  = WO + 1048576;                 // 4194304
  unsigned short* WF2  = WF1 + 4194304;                // 4194304
  unsigned short* ABUF = WF2 + 4194304;                // 7340032 (memory rows 0..1023, xn rows 1024..7167)
  unsigned short* QB   = ABUF + 7340032;               // 6291456 head-major [n][384][64]
  unsigned short* KB   = QB + 6291456;                 // 7340032 head-major [n][448][64]
  unsigned short* VB   = KB + 7340032;                 // 7340032 head-major [n][448][64]
  unsigned short* VT   = VB + 7340032;                 // 7340032 [n][64][448]
  unsigned short* ATTN = VT + 7340032;                 // 6291456
  float*          X2   = (float*)(ATTN + 6291456);     // 6291456 f32
  unsigned short* XN2  = ATTN;                         // alias (attn dead after out-proj)
  unsigned short* HB   = ABUF;                         // alias (A/q/k/v dead after attention)

  // weight + memory converts
  cvt_bf16<<<1024, 256, 0, stream>>>(q_w, WQ, 262144);
  cvt_bf16<<<1024, 256, 0, stream>>>(k_w, WK, 262144);
  cvt_bf16<<<1024, 256, 0, stream>>>(v_w, WV, 262144);
  cvt_bf16<<<1024, 256, 0, stream>>>(o_w, WO, 262144);
  cvt_bf16<<<4096, 256, 0, stream>>>(f1w, WF1, 1048576);
  cvt_bf16<<<4096, 256, 0, stream>>>(f2w, WF2, 1048576);
  cvt_bf16<<<1024, 256, 0, stream>>>(mem, ABUF, 262144);

  // LN1 -> xn (rows 1024.. of ABUF)
  ln_bf16<<<6144, 256, 0, stream>>>(x, ABUF + 1048576, ln1w, ln1b);

  // QKV projections -> head-major layouts (summary row is dead code)
  gemm_bt<4><<<dim3(8, 48), 256, 0, stream>>>(ABUF + 1048576, WQ, q_b, nullptr, QB, 6144, 1024, 1024, 0.125f);
  gemm_bt<4><<<dim3(8, 56), 256, 0, stream>>>(ABUF, WK, k_b, nullptr, KB, 7168, 1024, 1024, 1.f);
  gemm_bt<4><<<dim3(8, 56), 256, 0, stream>>>(ABUF, WV, v_b, nullptr, VB, 7168, 1024, 1024, 1.f);

  vtrans<<<dim3(7, 256), 256, 0, stream>>>(VB, VT);
  attn_kernel<<<6144, 256, 0, stream>>>(QB, KB, VT, ATTN);

  // out-proj + residual -> X2 (f32)
  gemm_bt<2><<<dim3(8, 48), 256, 0, stream>>>(ATTN, WO, o_b, x, X2, 6144, 1024, 1024, 1.f);

  // LN2 -> xn2
  ln_bf16<<<6144, 256, 0, stream>>>(X2, XN2, ln2w, ln2b);

  // FFN
  gemm_bt<3><<<dim3(32, 48), 256, 0, stream>>>(XN2, WF1, f1b, nullptr, HB, 6144, 4096, 1024, 1.f);
  gemm_bt<2><<<dim3(8, 48), 256, 0, stream>>>(HB, WF2, f2b, X2, d_out, 6144, 1024, 4096, 1.f);
}